// Round 1
// 66.319 us; speedup vs baseline: 1.0439x; 1.0439x over previous
//
#include <hip/hip_runtime.h>
#include <math.h>

#define TPB    256
#define IPT    2
#define ITILE  (TPB * IPT)        // 512 i-rows per block
#define JCHUNK 64                 // j-columns per block (= wave size)
#define RATIO  (ITILE / JCHUNK)   // 8

// Pairwise MarginRankingLoss, triangular (j>i) only — hinge is i<->j
// symmetric, so sum/count over j>i equals the reference ratio.
//
// R7 vs R6:
//  - IPT=2: each thread owns two i-rows (i0+tid, i0+TPB+tid); tile is
//    512x64, 1088 blocks (4.25 waves/SIMD). Halves LDS reads per pair and
//    gives two independent accumulator chains.
//  - NaN-poison moved from t to p: masked entries carry p=NaN, so
//    q = p_j - p_i is NaN whenever either side is masked and
//    fmaxf(NaN,0)=0 (IEEE maxnum) zeroes the hinge. The explicit
//    fmaf(0,dt,qr) poison op is gone -> 6 VALU/pair off-diag.
//  - Count is O(1) per thread everywhere: j-validity staged as a 64-bit
//    wave ballot; thread's count = popcll(suffix of mask above its i).
//    Diag sum gating is k > (i - j0) per unrolled iter (cmp+cndmask),
//    no per-pair ballots.
//  - Same accepted approximation as R6 (|dt|<eps ties between two valid
//    entries counted; ~19 of 28M pairs, ~3e-7 rel err), now uniform
//    across diag tiles too.
__global__ __launch_bounds__(TPB) void mrl_partial(
    const float* __restrict__ p, const float* __restrict__ t,
    const int* __restrict__ m, int B,
    float2* __restrict__ part)
{
    // ---- closed-form triangular mapping: block id -> (bi, off) ----
    // row bi has active chunks by in [RATIO*bi, CH); cum C(b) = A*b - 4*b*b
    const int CH = B / JCHUNK;          // 128 for B=8192
    const int A  = CH + RATIO / 2;      // 132
    const int ROWS = B / ITILE;         // 16
    const int id = blockIdx.x;

    const float f = sqrtf((float)(A * A - 16 * id));
    int bi = (int)((float)A - f) >> 3;  // (A - sqrt(A^2-16id))/8
    if (bi < 0) bi = 0;
    if (bi > ROWS - 1) bi = ROWS - 1;
    #define CFN(b) (A * (b) - 4 * (b) * (b))
    while (CFN(bi) > id) --bi;          // fixup fp rounding
    while (CFN(bi + 1) <= id) ++bi;
    const int off = id - CFN(bi);
    const int by  = RATIO * bi + off;
    const int i0  = bi * ITILE;
    const int j0  = by * JCHUNK;
    const bool diag = (off < RATIO);    // some pairs need the j>i gate

    // ---- stage j-chunk: (p_j or NaN, t_j) + validity ballot ----
    __shared__ float2 sj[JCHUNK];
    __shared__ unsigned long long smask;
    if (threadIdx.x < 64) {             // wave 0 exactly (JCHUNK == 64)
        const int j  = j0 + threadIdx.x;
        const int mj = m[j];
        sj[threadIdx.x] = make_float2(mj ? p[j] : __builtin_nanf(""), t[j]);
        const unsigned long long bal = __ballot(mj != 0);
        if (threadIdx.x == 0) smask = bal;
    }

    const int i_lo = i0 + threadIdx.x;
    const int i_hi = i_lo + TPB;
    const int mlo = m[i_lo];
    const int mhi = m[i_hi];
    const float pl = mlo ? p[i_lo] : __builtin_nanf("");
    const float ph = mhi ? p[i_hi] : __builtin_nanf("");
    const float tl = t[i_lo];
    const float th = t[i_hi];

    __syncthreads();
    const unsigned long long jm = smask;

    // ---- pair loop: 6 VALU/pair off-diag, +2 (cmp+cndmask) on diag ----
    float acc0 = 0.0f, acc1 = 0.0f;
    if (!diag) {
        #pragma unroll 8
        for (int k = 0; k < JCHUNK; ++k) {
            const float2 pt = sj[k];
            const float dt0 = tl - pt.y;
            const float q0  = pt.x - pl;                       // NaN if masked
            acc0 += fmaxf(fmaf(copysignf(1.0f, dt0), q0, 0.1f), 0.0f);
            const float dt1 = th - pt.y;
            const float q1  = pt.x - ph;
            acc1 += fmaxf(fmaf(copysignf(1.0f, dt1), q1, 0.1f), 0.0f);
        }
    } else {
        const int kl = i_lo - j0;       // include iff k > kl  (<=> j > i_lo)
        const int kh = i_hi - j0;
        #pragma unroll 8
        for (int k = 0; k < JCHUNK; ++k) {
            const float2 pt = sj[k];
            const float dt0 = tl - pt.y;
            const float q0  = pt.x - pl;
            const float h0  = fmaxf(fmaf(copysignf(1.0f, dt0), q0, 0.1f), 0.0f);
            acc0 += (k > kl) ? h0 : 0.0f;
            const float dt1 = th - pt.y;
            const float q1  = pt.x - ph;
            const float h1  = fmaxf(fmaf(copysignf(1.0f, dt1), q1, 0.1f), 0.0f);
            acc1 += (k > kh) ? h1 : 0.0f;
        }
    }

    // ---- O(1) per-thread pair count via suffix popcount of jm ----
    // #valid j with j > i in this chunk; off-diag blocks have idx < 0
    // (all 64 j above both i's) so the same code is the closed form.
    const int total_j = (int)__popcll(jm);
    int cnt = 0;
    if (mlo) {
        const int idx = i_lo - j0;
        cnt += (idx < 0) ? total_j
             : ((idx >= 63) ? 0 : (int)__popcll(jm >> (idx + 1)));
    }
    if (mhi) {
        const int idx = i_hi - j0;
        cnt += (idx < 0) ? total_j
             : ((idx >= 63) ? 0 : (int)__popcll(jm >> (idx + 1)));
    }

    // ---- block reduction: wave shuffle, then cross-wave via LDS ----
    float acc = acc0 + acc1;
    #pragma unroll
    for (int o = 32; o > 0; o >>= 1) {
        acc += __shfl_down(acc, o, 64);
        cnt += __shfl_down(cnt, o, 64);
    }

    __shared__ float wsum[TPB / 64];
    __shared__ int   wcnt[TPB / 64];
    const int lane = threadIdx.x & 63;
    const int wid  = threadIdx.x >> 6;
    if (lane == 0) { wsum[wid] = acc; wcnt[wid] = cnt; }
    __syncthreads();
    if (threadIdx.x == 0) {
        float a = 0.0f;
        int   c = 0;
        #pragma unroll
        for (int w = 0; w < TPB / 64; ++w) { a += wsum[w]; c += wcnt[w]; }
        part[id] = make_float2(a, (float)c);   // c <= 32768: exact in f32
    }
}

// Stage 2: single block reduces the partials in double and divides.
__global__ __launch_bounds__(256) void mrl_final(
    const float2* __restrict__ part, int nblk, float* __restrict__ out)
{
    double a = 0.0, c = 0.0;
    for (int k = threadIdx.x; k < nblk; k += 256) {
        const float2 v = part[k];
        a += (double)v.x;
        c += (double)v.y;
    }
    #pragma unroll
    for (int o = 32; o > 0; o >>= 1) {
        a += __shfl_down(a, o, 64);
        c += __shfl_down(c, o, 64);
    }
    __shared__ double sa[4];
    __shared__ double sc[4];
    const int lane = threadIdx.x & 63;
    const int wid  = threadIdx.x >> 6;
    if (lane == 0) { sa[wid] = a; sc[wid] = c; }
    __syncthreads();
    if (threadIdx.x == 0) {
        double A = 0.0, C = 0.0;
        #pragma unroll
        for (int w = 0; w < 4; ++w) { A += sa[w]; C += sc[w]; }
        out[0] = (float)(A / fmax(C, 1.0));
    }
}

extern "C" void kernel_launch(void* const* d_in, const int* in_sizes, int n_in,
                              void* d_out, int out_size, void* d_ws, size_t ws_size,
                              hipStream_t stream)
{
    const float* p = (const float*)d_in[0];
    const float* t = (const float*)d_in[1];
    const int*   m = (const int*)d_in[2];
    const int B = in_sizes[0];   // 8192; tiling assumes B % 512 == 0

    const int rows = B / ITILE;                        // 16
    const int ch   = B / JCHUNK;                       // 64-col chunks: 128
    int nactive = 0;
    for (int b = 0; b < rows; ++b) nactive += ch - RATIO * b;   // 1088

    float2* part = (float2*)d_ws;

    mrl_partial<<<nactive, TPB, 0, stream>>>(p, t, m, B, part);
    mrl_final<<<1, 256, 0, stream>>>(part, nactive, (float*)d_out);
}